// Round 1
// baseline (1159.004 us; speedup 1.0000x reference)
//
#include <hip/hip_runtime.h>

#define BN_S 0.9999950000374997f

typedef __attribute__((ext_vector_type(8))) short bf16x8;
typedef __attribute__((ext_vector_type(4))) float f32x4;

__device__ inline short f2bf(float f) {
    union { float f; unsigned u; } v; v.f = f;
    return (short)((v.u + 0x7FFFu + ((v.u >> 16) & 1u)) >> 16);
}

// ---------------- gates: top-k mask + masked softmax -> p[14][32][8] ----------
__global__ void gates_k(const float* __restrict__ g, const int* __restrict__ topp,
                        float* __restrict__ p)
{
    int t = blockIdx.x * blockDim.x + threadIdx.x;
    if (t >= 14 * 32) return;
    int top = topp[0];
    float v[8]; bool sel[8];
    for (int o = 0; o < 8; ++o) { v[o] = g[t * 8 + o]; sel[o] = false; }
    for (int it = 0; it < top; ++it) {
        int bi = 0; float bv = -3.4e38f;
        for (int o = 0; o < 8; ++o)
            if (!sel[o] && v[o] > bv) { bv = v[o]; bi = o; }
        sel[bi] = true;
    }
    float mx = -3.4e38f;
    for (int o = 0; o < 8; ++o) if (sel[o]) mx = fmaxf(mx, v[o]);
    float e[8]; float sum = 0.0f;
    for (int o = 0; o < 8; ++o) { e[o] = sel[o] ? expf(v[o] - mx) : 0.0f; sum += e[o]; }
    for (int o = 0; o < 8; ++o) p[t * 8 + o] = e[o] / sum;
}

// ---------------- one-time: convert all pointwise weights f32 -> bf16 --------
__global__ void cvt_k(const float* __restrict__ s3p1, const float* __restrict__ s3p2,
                      const float* __restrict__ s5p1, const float* __restrict__ s5p2,
                      const float* __restrict__ d3p,  const float* __restrict__ d5p,
                      const float* __restrict__ pre0, const float* __restrict__ pre1,
                      short* __restrict__ wb, short* __restrict__ wpre)
{
    const int which = blockIdx.y;
    const float* src; short* dst; int n;
    switch (which) {
        case 0: src = s3p1; dst = wb;               n = 229376; break;
        case 1: src = s3p2; dst = wb + 229376;      n = 229376; break;
        case 2: src = s5p1; dst = wb + 2 * 229376;  n = 229376; break;
        case 3: src = s5p2; dst = wb + 3 * 229376;  n = 229376; break;
        case 4: src = d3p;  dst = wb + 4 * 229376;  n = 229376; break;
        case 5: src = d5p;  dst = wb + 5 * 229376;  n = 229376; break;
        case 6: src = pre0; dst = wpre;             n = 65536;  break;
        default:src = pre1; dst = wpre + 65536;     n = 65536;  break;
    }
    for (int i = blockIdx.x * 256 + threadIdx.x; i < n; i += gridDim.x * 256)
        dst[i] = f2bf(src[i]);
}

// ---------------- preprocess: K=512 GEMM, relu on input, both states ---------
__global__ void __launch_bounds__(256)
pre_k(const float* __restrict__ s0, const float* __restrict__ s1,
      const short* __restrict__ wpre,
      float* __restrict__ s0p, float* __restrict__ s1p)
{
    const int z = blockIdx.z;
    const int b = z & 31, which = z >> 5;
    const float* in = which ? s1 : s0;
    const short* w = wpre + which * 65536;
    float* outp = (which ? s1p : s0p) + (long)b * 131072;

    const int tid = threadIdx.x;
    const int wave = tid >> 6, lane = tid & 63;
    const int quad = lane >> 4, l16 = lane & 15;
    const int co0 = blockIdx.y * 32 + (wave & 1) * 16;
    const int n0  = blockIdx.x * 128 + (wave >> 1) * 64;
    const float* __restrict__ xb = in + (long)b * 524288;

    f32x4 acc[4] = {{0,0,0,0},{0,0,0,0},{0,0,0,0},{0,0,0,0}};
    for (int k0 = 0; k0 < 512; k0 += 32) {
        bf16x8 af = *(const bf16x8*)(w + (long)(co0 + l16) * 512 + k0 + quad * 8);
        const float* xc = xb + (long)(k0 + quad * 8) * 1024 + n0 + l16;
#pragma unroll
        for (int s = 0; s < 4; ++s) {
            bf16x8 bfv;
#pragma unroll
            for (int j = 0; j < 8; ++j) bfv[j] = f2bf(fmaxf(xc[(long)j * 1024 + s * 16], 0.0f));
            acc[s] = __builtin_amdgcn_mfma_f32_16x16x32_bf16(af, bfv, acc[s], 0, 0, 0);
        }
    }
#pragma unroll
    for (int s = 0; s < 4; ++s)
#pragma unroll
        for (int r = 0; r < 4; ++r)
            outp[(long)(co0 + quad * 4 + r) * 1024 + n0 + s * 16 + l16] = acc[s][r] * BN_S;
}

// ---------------- depthwise helper (compile-time shape) ----------------------
template<int KS, int DIL, int PAD>
__device__ inline float dwc(const float* t, const float* w, int h, int wx) {
    float s = 0.0f;
#pragma unroll
    for (int ki = 0; ki < KS; ++ki) {
        int y = h - PAD + ki * DIL;
        if ((unsigned)y < 32u) {
#pragma unroll
            for (int kj = 0; kj < KS; ++kj) {
                int x = wx - PAD + kj * DIL;
                if ((unsigned)x < 32u) s += w[ki * KS + kj] * t[(y << 5) + x];
            }
        }
    }
    return s;
}

// ---------------- stage 1: 4 first-stage dwconvs sharing one relu(x) tile ----
// X layout: [b][seg][128][1024] bf16, seg: 0=sep3-dw1, 1=sep5-dw1, 2=dil3*g6*BN, 3=dil5*g7*BN
__global__ void __launch_bounds__(256)
dw1_k(const float* __restrict__ x, long xbs,
      const float* __restrict__ w0, const float* __restrict__ w1,
      const float* __restrict__ w2, const float* __restrict__ w3,
      short* __restrict__ X, const float* __restrict__ pm)
{
    const int c = blockIdx.x, b = blockIdx.y;
    const float g4 = pm[b * 8 + 4], g5 = pm[b * 8 + 5];
    const float g6 = pm[b * 8 + 6], g7 = pm[b * 8 + 7];
    if (g4 == 0.f && g5 == 0.f && g6 == 0.f && g7 == 0.f) return;
    __shared__ float t[1024];
    __shared__ float wl[4][25];
    const int tid = threadIdx.x;
    const float* src = x + (long)b * xbs + (long)c * 1024;
    for (int i = tid; i < 1024; i += 256) t[i] = fmaxf(src[i], 0.0f);
    if (tid < 9)                          wl[0][tid]       = w0[(long)c * 9  + tid];
    else if (tid >= 64 && tid < 89)       wl[1][tid - 64]  = w1[(long)c * 25 + tid - 64];
    else if (tid >= 128 && tid < 137)     wl[2][tid - 128] = w2[(long)c * 9  + tid - 128];
    else if (tid >= 192 && tid < 217)     wl[3][tid - 192] = w3[(long)c * 25 + tid - 192];
    __syncthreads();
    short* dst = X + (long)b * 524288 + (long)c * 1024;
    const float s6 = g6 * BN_S, s7 = g7 * BN_S;
    for (int i = tid; i < 1024; i += 256) {
        int h = i >> 5, wx = i & 31;
        if (g4 != 0.f) dst[i]          = f2bf(dwc<3,1,1>(t, wl[0], h, wx));
        if (g5 != 0.f) dst[131072 + i] = f2bf(dwc<5,1,2>(t, wl[1], h, wx));
        if (g6 != 0.f) dst[262144 + i] = f2bf(s6 * dwc<3,2,2>(t, wl[2], h, wx));
        if (g7 != 0.f) dst[393216 + i] = f2bf(s7 * dwc<5,2,4>(t, wl[3], h, wx));
    }
}

// ---------------- stage 2: pw1 GEMMs for sep3/sep5, BN+relu folded -----------
// y layout: [b][u][128][1024] f32 (already relu'd)
__global__ void __launch_bounds__(256)
gemm_pw1_k(const short* __restrict__ X,
           const short* __restrict__ wA, const short* __restrict__ wB,
           float* __restrict__ y, const float* __restrict__ pm)
{
    const int b = blockIdx.z;
    const int u = blockIdx.y >> 2, cot = blockIdx.y & 3;
    if (pm[b * 8 + 4 + u] == 0.f) return;
    const int tid = threadIdx.x;
    const int wave = tid >> 6, lane = tid & 63;
    const int quad = lane >> 4, l16 = lane & 15;
    const int co0 = cot * 32 + (wave & 1) * 16;
    const int n0  = blockIdx.x * 128 + (wave >> 1) * 64;
    const short* w = u ? wB : wA;
    const short* xb = X + (long)b * 524288 + (long)u * 131072;

    f32x4 acc[4] = {{0,0,0,0},{0,0,0,0},{0,0,0,0},{0,0,0,0}};
    for (int k0 = 0; k0 < 128; k0 += 32) {
        bf16x8 af = *(const bf16x8*)(w + (co0 + l16) * 128 + k0 + quad * 8);
        const short* xc = xb + (long)(k0 + quad * 8) * 1024 + n0 + l16;
#pragma unroll
        for (int s = 0; s < 4; ++s) {
            bf16x8 bfv;
#pragma unroll
            for (int j = 0; j < 8; ++j) bfv[j] = xc[j * 1024 + s * 16];
            acc[s] = __builtin_amdgcn_mfma_f32_16x16x32_bf16(af, bfv, acc[s], 0, 0, 0);
        }
    }
    float* dst = y + ((long)b * 2 + u) * 131072;
#pragma unroll
    for (int s = 0; s < 4; ++s)
#pragma unroll
        for (int r = 0; r < 4; ++r)
            dst[(long)(co0 + quad * 4 + r) * 1024 + n0 + s * 16 + l16] =
                fmaxf(acc[s][r] * BN_S, 0.0f);
}

// ---------------- stage 3: second dwconvs (input already relu'd), scale g*BN -
__global__ void __launch_bounds__(256)
dw2_k(const float* __restrict__ y,
      const float* __restrict__ w3_, const float* __restrict__ w5_,
      short* __restrict__ X, const float* __restrict__ pm)
{
    const int c = blockIdx.x, b = blockIdx.y, u = blockIdx.z;
    const float g = pm[b * 8 + 4 + u];
    if (g == 0.f) return;
    __shared__ float t[1024];
    __shared__ float wl[25];
    const int tid = threadIdx.x;
    const float* src = y + ((long)b * 2 + u) * 131072 + (long)c * 1024;
    for (int i = tid; i < 1024; i += 256) t[i] = src[i];
    if (u == 0) { if (tid < 9)  wl[tid] = w3_[(long)c * 9  + tid]; }
    else        { if (tid < 25) wl[tid] = w5_[(long)c * 25 + tid]; }
    __syncthreads();
    const float sc = g * BN_S;
    short* dst = X + (long)b * 524288 + (long)u * 131072 + (long)c * 1024;
    if (u == 0) {
        for (int i = tid; i < 1024; i += 256)
            dst[i] = f2bf(sc * dwc<3,1,1>(t, wl, i >> 5, i & 31));
    } else {
        for (int i = tid; i < 1024; i += 256)
            dst[i] = f2bf(sc * dwc<5,1,2>(t, wl, i >> 5, i & 31));
    }
}

// ---------------- stage 4: fused K=512 gated GEMM, accumulates into state ----
__global__ void __launch_bounds__(256)
gemm_final_k(const short* __restrict__ X,
             const short* __restrict__ w0, const short* __restrict__ w1,
             const short* __restrict__ w2, const short* __restrict__ w3,
             float* __restrict__ outp, const float* __restrict__ pm)
{
    const int b = blockIdx.z;
    const float g0 = pm[b * 8 + 4], g1 = pm[b * 8 + 5];
    const float g2 = pm[b * 8 + 6], g3 = pm[b * 8 + 7];
    if (g0 == 0.f && g1 == 0.f && g2 == 0.f && g3 == 0.f) return;
    const int tid = threadIdx.x;
    const int wave = tid >> 6, lane = tid & 63;
    const int quad = lane >> 4, l16 = lane & 15;
    const int co0 = blockIdx.y * 32 + (wave & 1) * 16;
    const int n0  = blockIdx.x * 128 + (wave >> 1) * 64;
    const short* xb = X + (long)b * 524288;

    f32x4 acc[4] = {{0,0,0,0},{0,0,0,0},{0,0,0,0},{0,0,0,0}};
    auto do_seg = [&](float gg, const short* w, const short* xs) {
        if (gg == 0.f) return;
        for (int k0 = 0; k0 < 128; k0 += 32) {
            bf16x8 af = *(const bf16x8*)(w + (co0 + l16) * 128 + k0 + quad * 8);
            const short* xc = xs + (long)(k0 + quad * 8) * 1024 + n0 + l16;
#pragma unroll
            for (int s = 0; s < 4; ++s) {
                bf16x8 bfv;
#pragma unroll
                for (int j = 0; j < 8; ++j) bfv[j] = xc[j * 1024 + s * 16];
                acc[s] = __builtin_amdgcn_mfma_f32_16x16x32_bf16(af, bfv, acc[s], 0, 0, 0);
            }
        }
    };
    do_seg(g0, w0, xb);
    do_seg(g1, w1, xb + 131072);
    do_seg(g2, w2, xb + 262144);
    do_seg(g3, w3, xb + 393216);

#pragma unroll
    for (int s = 0; s < 4; ++s)
#pragma unroll
        for (int r = 0; r < 4; ++r) {
            long idx = (long)b * 524288 + (long)(co0 + quad * 4 + r) * 1024
                     + n0 + s * 16 + l16;
            outp[idx] += acc[s][r];
        }
}

// ---------------- pools + skip for ALL branches of a step; overwrites dst ----
struct PoolA { const float* xs[5]; long xbs[5]; int goff[5]; int cnt; };

__global__ void __launch_bounds__(256)
pool_skip_all_k(PoolA a, const float* __restrict__ p,
                float* __restrict__ so, long out_bs)
{
    const int c = blockIdx.x, b = blockIdx.y, tid = threadIdx.x;
    __shared__ float t[1024];
    float acc[4] = {0.f, 0.f, 0.f, 0.f};
    for (int j = 0; j < a.cnt; ++j) {
        const float* g = p + a.goff[j] + b * 8;
        float w1 = g[1] * BN_S, w2 = g[2] * BN_S, w3 = g[3];
        if (w1 == 0.f && w2 == 0.f && w3 == 0.f) continue;
        const float* src = a.xs[j] + (long)b * a.xbs[j] + (long)c * 1024;
        __syncthreads();
        for (int i = tid; i < 1024; i += 256) t[i] = src[i];
        __syncthreads();
#pragma unroll
        for (int e = 0; e < 4; ++e) {
            int i = tid + e * 256;
            int h = i >> 5, wx = i & 31;
            int y0 = max(h - 1, 0), y1 = min(h + 1, 31);
            int x0 = max(wx - 1, 0), x1 = min(wx + 1, 31);
            float mx = -3.4e38f, sm = 0.0f;
            for (int y = y0; y <= y1; ++y)
                for (int x = x0; x <= x1; ++x) {
                    float v = t[(y << 5) + x];
                    mx = fmaxf(mx, v); sm += v;
                }
            float cntc = (float)((y1 - y0 + 1) * (x1 - x0 + 1));
            acc[e] += w1 * mx + w2 * (sm / cntc) + w3 * t[i];
        }
    }
    float* dst = so + (long)b * out_bs + (long)c * 1024;
#pragma unroll
    for (int e = 0; e < 4; ++e) dst[tid + e * 256] = acc[e];
}

extern "C" void kernel_launch(void* const* d_in, const int* in_sizes, int n_in,
                              void* d_out, int out_size, void* d_ws, size_t ws_size,
                              hipStream_t stream)
{
    const float* s0   = (const float*)d_in[0];
    const float* s1   = (const float*)d_in[1];
    const float* gts  = (const float*)d_in[2];
    const float* pre0 = (const float*)d_in[3];
    const float* pre1 = (const float*)d_in[4];
    const float* s3d1 = (const float*)d_in[5];
    const float* s3p1 = (const float*)d_in[6];
    const float* s3d2 = (const float*)d_in[7];
    const float* s3p2 = (const float*)d_in[8];
    const float* s5d1 = (const float*)d_in[9];
    const float* s5p1 = (const float*)d_in[10];
    const float* s5d2 = (const float*)d_in[11];
    const float* s5p2 = (const float*)d_in[12];
    const float* d3d  = (const float*)d_in[13];
    const float* d3p  = (const float*)d_in[14];
    const float* d5d  = (const float*)d_in[15];
    const float* d5p  = (const float*)d_in[16];
    const int*   topp = (const int*)d_in[17];
    float* out = (float*)d_out;

    float* ws   = (float*)d_ws;
    float* p    = ws;                          // 4096 floats (3584 used)
    float* s0p  = ws + 4096;                   // [32][128][1024] f32
    float* s1p  = s0p + 4194304;
    float* yb   = s1p + 4194304;               // [32][2][128][1024] f32
    short* X    = (short*)(yb + 8388608);      // [32][4][128][1024] bf16
    short* wb   = X + 16777216;                // 6 x [14][128][128] bf16
    short* wpre = wb + 1376256;                // 2 x [128][512] bf16

    gates_k<<<2, 256, 0, stream>>>(gts, topp, p);
    cvt_k<<<dim3(224, 8), 256, 0, stream>>>(s3p1, s3p2, s5p1, s5p2, d3p, d5p,
                                            pre0, pre1, wb, wpre);
    pre_k<<<dim3(8, 4, 64), 256, 0, stream>>>(s0, s1, wpre, s0p, s1p);

    const long SB = 131072L, OB = 524288L;
    const float* stp[6]; long sbs[6];
    stp[0] = s0p; sbs[0] = SB;
    stp[1] = s1p; sbs[1] = SB;

    int offset = 0;
    for (int i = 0; i < 4; ++i) {
        float* so = out + (long)i * 131072;
        int cnt = 2 + i;

        PoolA pa{};
        for (int j = 0; j < cnt; ++j) {
            pa.xs[j] = stp[j]; pa.xbs[j] = sbs[j]; pa.goff[j] = (offset + j) * 256;
        }
        pa.cnt = cnt;
        pool_skip_all_k<<<dim3(128, 32), 256, 0, stream>>>(pa, p, so, OB);

        for (int j = 0; j < cnt; ++j) {
            int m = offset + j;
            const float* pm = p + (long)m * 256;
            dw1_k<<<dim3(128, 32), 256, 0, stream>>>(stp[j], sbs[j],
                s3d1 + (long)m * 1152, s5d1 + (long)m * 3200,
                d3d  + (long)m * 1152, d5d  + (long)m * 3200, X, pm);
            gemm_pw1_k<<<dim3(8, 8, 32), 256, 0, stream>>>(X,
                wb + (long)m * 16384, wb + 2L * 229376 + (long)m * 16384, yb, pm);
            dw2_k<<<dim3(128, 32, 2), 256, 0, stream>>>(yb,
                s3d2 + (long)m * 1152, s5d2 + (long)m * 3200, X, pm);
            gemm_final_k<<<dim3(8, 4, 32), 256, 0, stream>>>(X,
                wb + 1L * 229376 + (long)m * 16384, wb + 3L * 229376 + (long)m * 16384,
                wb + 4L * 229376 + (long)m * 16384, wb + 5L * 229376 + (long)m * 16384,
                so, pm);
        }
        stp[2 + i] = so; sbs[2 + i] = OB;
        offset += cnt;
    }
}

// Round 2
// 935.229 us; speedup vs baseline: 1.2393x; 1.2393x over previous
//
#include <hip/hip_runtime.h>

#define BN_S 0.9999950000374997f

typedef __attribute__((ext_vector_type(8))) short bf16x8;
typedef __attribute__((ext_vector_type(4))) float f32x4;

__device__ inline short f2bf(float f) {
    union { float f; unsigned u; } v; v.f = f;
    return (short)((v.u + 0x7FFFu + ((v.u >> 16) & 1u)) >> 16);
}

// ---------------- gates: top-k mask + masked softmax -> p[14][32][8] ----------
__global__ void gates_k(const float* __restrict__ g, const int* __restrict__ topp,
                        float* __restrict__ p)
{
    int t = blockIdx.x * blockDim.x + threadIdx.x;
    if (t >= 14 * 32) return;
    int top = topp[0];
    float v[8]; bool sel[8];
    for (int o = 0; o < 8; ++o) { v[o] = g[t * 8 + o]; sel[o] = false; }
    for (int it = 0; it < top; ++it) {
        int bi = 0; float bv = -3.4e38f;
        for (int o = 0; o < 8; ++o)
            if (!sel[o] && v[o] > bv) { bv = v[o]; bi = o; }
        sel[bi] = true;
    }
    float mx = -3.4e38f;
    for (int o = 0; o < 8; ++o) if (sel[o]) mx = fmaxf(mx, v[o]);
    float e[8]; float sum = 0.0f;
    for (int o = 0; o < 8; ++o) { e[o] = sel[o] ? expf(v[o] - mx) : 0.0f; sum += e[o]; }
    for (int o = 0; o < 8; ++o) p[t * 8 + o] = e[o] / sum;
}

// ---------------- one-time: convert all pointwise weights f32 -> bf16 --------
__global__ void cvt_k(const float* __restrict__ s3p1, const float* __restrict__ s3p2,
                      const float* __restrict__ s5p1, const float* __restrict__ s5p2,
                      const float* __restrict__ d3p,  const float* __restrict__ d5p,
                      const float* __restrict__ pre0, const float* __restrict__ pre1,
                      short* __restrict__ wb, short* __restrict__ wpre)
{
    const int which = blockIdx.y;
    const float* src; short* dst; int n;
    switch (which) {
        case 0: src = s3p1; dst = wb;               n = 229376; break;
        case 1: src = s3p2; dst = wb + 229376;      n = 229376; break;
        case 2: src = s5p1; dst = wb + 2 * 229376;  n = 229376; break;
        case 3: src = s5p2; dst = wb + 3 * 229376;  n = 229376; break;
        case 4: src = d3p;  dst = wb + 4 * 229376;  n = 229376; break;
        case 5: src = d5p;  dst = wb + 5 * 229376;  n = 229376; break;
        case 6: src = pre0; dst = wpre;             n = 65536;  break;
        default:src = pre1; dst = wpre + 65536;     n = 65536;  break;
    }
    for (int i = blockIdx.x * 256 + threadIdx.x; i < n; i += gridDim.x * 256)
        dst[i] = f2bf(src[i]);
}

// ---------------- preprocess: K=512 GEMM, relu+cvt fused via LDS staging -----
// grid (8 n-tiles, 1, 64): z -> b | which. Block computes all 128 co.
// LDS B tile [128 n][32 k] bf16, row stride 40 shorts (16B-aligned, 2-way banks).
__global__ void __launch_bounds__(256)
pre_k(const float* __restrict__ s0, const float* __restrict__ s1,
      const short* __restrict__ wpre,
      float* __restrict__ s0p, float* __restrict__ s1p)
{
    const int z = blockIdx.z;
    const int b = z & 31, which = z >> 5;
    const float* in = (which ? s1 : s0) + (long)b * 524288;
    const short* w = wpre + which * 65536;
    float* outp = (which ? s1p : s0p) + (long)b * 131072;

    const int tid = threadIdx.x;
    const int wave = tid >> 6, lane = tid & 63;
    const int quad = lane >> 4, l16 = lane & 15;
    const int n0 = blockIdx.x * 128;

    __shared__ short bt[128 * 40];
    const int tn = tid & 127, tk = (tid >> 7) * 16;

    f32x4 acc[16];
#pragma unroll
    for (int i = 0; i < 16; ++i) acc[i] = (f32x4){0.f, 0.f, 0.f, 0.f};

    for (int k0 = 0; k0 < 512; k0 += 32) {
        __syncthreads();
        bf16x8 lo, hi;
#pragma unroll
        for (int kk = 0; kk < 8; ++kk) {
            lo[kk] = f2bf(fmaxf(in[(long)(k0 + tk + kk) * 1024 + n0 + tn], 0.0f));
            hi[kk] = f2bf(fmaxf(in[(long)(k0 + tk + 8 + kk) * 1024 + n0 + tn], 0.0f));
        }
        *(bf16x8*)&bt[tn * 40 + tk]     = lo;
        *(bf16x8*)&bt[tn * 40 + tk + 8] = hi;
        __syncthreads();
#pragma unroll
        for (int cf = 0; cf < 2; ++cf) {
            bf16x8 af = *(const bf16x8*)(w + (long)(wave * 32 + cf * 16 + l16) * 512
                                           + k0 + quad * 8);
#pragma unroll
            for (int s = 0; s < 8; ++s) {
                bf16x8 bfv = *(const bf16x8*)&bt[(s * 16 + l16) * 40 + quad * 8];
                acc[cf * 8 + s] = __builtin_amdgcn_mfma_f32_16x16x32_bf16(
                                      af, bfv, acc[cf * 8 + s], 0, 0, 0);
            }
        }
    }
#pragma unroll
    for (int cf = 0; cf < 2; ++cf)
#pragma unroll
        for (int s = 0; s < 8; ++s)
#pragma unroll
            for (int r = 0; r < 4; ++r)
                outp[(long)(wave * 32 + cf * 16 + quad * 4 + r) * 1024
                     + n0 + s * 16 + l16] = acc[cf * 8 + s][r] * BN_S;
}

// ---------------- depthwise helper (compile-time shape) ----------------------
template<int KS, int DIL, int PAD>
__device__ inline float dwc(const float* t, const float* w, int h, int wx) {
    float s = 0.0f;
#pragma unroll
    for (int ki = 0; ki < KS; ++ki) {
        int y = h - PAD + ki * DIL;
        if ((unsigned)y < 32u) {
#pragma unroll
            for (int kj = 0; kj < KS; ++kj) {
                int x = wx - PAD + kj * DIL;
                if ((unsigned)x < 32u) s += w[ki * KS + kj] * t[(y << 5) + x];
            }
        }
    }
    return s;
}

// ---------------- branch batch descriptor ------------------------------------
struct BranchA {
    const float* xs[5]; long xbs[5];
    int goff[5]; int m[5]; int nb;
};

// X slot layout per branch: [b 32][seg 4][c 128][n 1024] bf16, slot = 16,777,216 sh
// yb slot layout per branch: [b 32][u 2][c 128][n 1024] f32, slot = 8,388,608 f

// ---------------- stage 1: 4 first-stage dwconvs, all branches ---------------
__global__ void __launch_bounds__(256)
dw1_all(BranchA a, const float* __restrict__ s3d1, const float* __restrict__ s5d1,
        const float* __restrict__ d3d, const float* __restrict__ d5d,
        short* __restrict__ X, const float* __restrict__ p)
{
    const int c = blockIdx.x, b = blockIdx.y, j = blockIdx.z;
    const float* pm = p + a.goff[j] + b * 8;
    const float g4 = pm[4], g5 = pm[5], g6 = pm[6], g7 = pm[7];
    if (g4 == 0.f && g5 == 0.f && g6 == 0.f && g7 == 0.f) return;
    const int m = a.m[j];
    __shared__ float t[1024];
    __shared__ float wl[4][25];
    const int tid = threadIdx.x;
    const float* src = a.xs[j] + (long)b * a.xbs[j] + (long)c * 1024;
    for (int i = tid; i < 1024; i += 256) t[i] = fmaxf(src[i], 0.0f);
    if (tid < 9)                      wl[0][tid]     = s3d1[(long)m * 1152 + (long)c * 9 + tid];
    else if (tid >= 64 && tid < 89)   wl[1][tid-64]  = s5d1[(long)m * 3200 + (long)c * 25 + tid - 64];
    else if (tid >= 128 && tid < 137) wl[2][tid-128] = d3d[(long)m * 1152 + (long)c * 9 + tid - 128];
    else if (tid >= 192 && tid < 217) wl[3][tid-192] = d5d[(long)m * 3200 + (long)c * 25 + tid - 192];
    __syncthreads();
    short* dst = X + (long)j * 16777216 + (long)b * 524288 + (long)c * 1024;
    const float s6 = g6 * BN_S, s7 = g7 * BN_S;
    for (int i = tid; i < 1024; i += 256) {
        int h = i >> 5, wx = i & 31;
        if (g4 != 0.f) dst[i]          = f2bf(dwc<3,1,1>(t, wl[0], h, wx));
        if (g5 != 0.f) dst[131072 + i] = f2bf(dwc<5,1,2>(t, wl[1], h, wx));
        if (g6 != 0.f) dst[262144 + i] = f2bf(s6 * dwc<3,2,2>(t, wl[2], h, wx));
        if (g7 != 0.f) dst[393216 + i] = f2bf(s7 * dwc<5,2,4>(t, wl[3], h, wx));
    }
}

// ---------------- stage 2: pw1 GEMMs (sep3/sep5), all branches ---------------
__global__ void __launch_bounds__(256)
pw1_all(BranchA a, const short* __restrict__ X, const short* __restrict__ wb,
        float* __restrict__ yb, const float* __restrict__ p)
{
    const int z = blockIdx.z, b = z & 31, j = z >> 5;
    const int u = blockIdx.y >> 2, cot = blockIdx.y & 3;
    if (p[a.goff[j] + b * 8 + 4 + u] == 0.f) return;
    const int tid = threadIdx.x;
    const int wave = tid >> 6, lane = tid & 63;
    const int quad = lane >> 4, l16 = lane & 15;
    const int co0 = cot * 32 + (wave & 1) * 16;
    const int n0  = blockIdx.x * 128 + (wave >> 1) * 64;
    const short* w = wb + (u ? 2L * 229376 : 0L) + (long)a.m[j] * 16384;
    const short* xb = X + (long)j * 16777216 + (long)b * 524288 + (long)u * 131072;

    f32x4 acc[4] = {{0,0,0,0},{0,0,0,0},{0,0,0,0},{0,0,0,0}};
    for (int k0 = 0; k0 < 128; k0 += 32) {
        bf16x8 af = *(const bf16x8*)(w + (co0 + l16) * 128 + k0 + quad * 8);
        const short* xc = xb + (long)(k0 + quad * 8) * 1024 + n0 + l16;
#pragma unroll
        for (int s = 0; s < 4; ++s) {
            bf16x8 bfv;
#pragma unroll
            for (int jj = 0; jj < 8; ++jj) bfv[jj] = xc[jj * 1024 + s * 16];
            acc[s] = __builtin_amdgcn_mfma_f32_16x16x32_bf16(af, bfv, acc[s], 0, 0, 0);
        }
    }
    float* dst = yb + (long)j * 8388608 + ((long)b * 2 + u) * 131072;
#pragma unroll
    for (int s = 0; s < 4; ++s)
#pragma unroll
        for (int r = 0; r < 4; ++r)
            dst[(long)(co0 + quad * 4 + r) * 1024 + n0 + s * 16 + l16] =
                fmaxf(acc[s][r] * BN_S, 0.0f);
}

// ---------------- stage 3: second dwconvs, all branches ----------------------
__global__ void __launch_bounds__(256)
dw2_all(BranchA a, const float* __restrict__ yb,
        const float* __restrict__ s3d2, const float* __restrict__ s5d2,
        short* __restrict__ X, const float* __restrict__ p)
{
    const int c = blockIdx.x, b = blockIdx.y;
    const int z = blockIdx.z, u = z & 1, j = z >> 1;
    const float g = p[a.goff[j] + b * 8 + 4 + u];
    if (g == 0.f) return;
    const int m = a.m[j];
    __shared__ float t[1024];
    __shared__ float wl[25];
    const int tid = threadIdx.x;
    const float* src = yb + (long)j * 8388608 + ((long)b * 2 + u) * 131072 + (long)c * 1024;
    for (int i = tid; i < 1024; i += 256) t[i] = src[i];
    if (u == 0) { if (tid < 9)  wl[tid] = s3d2[(long)m * 1152 + (long)c * 9  + tid]; }
    else        { if (tid < 25) wl[tid] = s5d2[(long)m * 3200 + (long)c * 25 + tid]; }
    __syncthreads();
    const float sc = g * BN_S;
    short* dst = X + (long)j * 16777216 + (long)b * 524288 + (long)u * 131072 + (long)c * 1024;
    if (u == 0) {
        for (int i = tid; i < 1024; i += 256)
            dst[i] = f2bf(sc * dwc<3,1,1>(t, wl, i >> 5, i & 31));
    } else {
        for (int i = tid; i < 1024; i += 256)
            dst[i] = f2bf(sc * dwc<5,1,2>(t, wl, i >> 5, i & 31));
    }
}

// ---------------- stage 4: fused gated GEMM over all branches & segs ---------
// ONE read-modify-write of the output per chunk (not per branch).
__global__ void __launch_bounds__(256)
final_all(BranchA a, const short* __restrict__ X, const short* __restrict__ wb,
          float* __restrict__ outp, const float* __restrict__ p)
{
    const int b = blockIdx.z;
    const int tid = threadIdx.x;
    const int wave = tid >> 6, lane = tid & 63;
    const int quad = lane >> 4, l16 = lane & 15;
    const int co0 = blockIdx.y * 32 + (wave & 1) * 16;
    const int n0  = blockIdx.x * 128 + (wave >> 1) * 64;

    f32x4 acc[4] = {{0,0,0,0},{0,0,0,0},{0,0,0,0},{0,0,0,0}};
    bool any = false;
    for (int j = 0; j < a.nb; ++j) {
        const float* pm = p + a.goff[j] + b * 8;
        const short* xj = X + (long)j * 16777216 + (long)b * 524288;
        const long wm = (long)a.m[j] * 16384;
        const short* ws_[4] = { wb + 1L * 229376 + wm, wb + 3L * 229376 + wm,
                                wb + 4L * 229376 + wm, wb + 5L * 229376 + wm };
#pragma unroll
        for (int seg = 0; seg < 4; ++seg) {
            if (pm[4 + seg] == 0.f) continue;
            any = true;
            const short* w = ws_[seg];
            const short* xs = xj + (long)seg * 131072;
            for (int k0 = 0; k0 < 128; k0 += 32) {
                bf16x8 af = *(const bf16x8*)(w + (co0 + l16) * 128 + k0 + quad * 8);
                const short* xc = xs + (long)(k0 + quad * 8) * 1024 + n0 + l16;
#pragma unroll
                for (int s = 0; s < 4; ++s) {
                    bf16x8 bfv;
#pragma unroll
                    for (int jj = 0; jj < 8; ++jj) bfv[jj] = xc[jj * 1024 + s * 16];
                    acc[s] = __builtin_amdgcn_mfma_f32_16x16x32_bf16(af, bfv, acc[s], 0, 0, 0);
                }
            }
        }
    }
    if (!any) return;
#pragma unroll
    for (int s = 0; s < 4; ++s)
#pragma unroll
        for (int r = 0; r < 4; ++r) {
            long idx = (long)b * 524288 + (long)(co0 + quad * 4 + r) * 1024
                     + n0 + s * 16 + l16;
            outp[idx] += acc[s][r];
        }
}

// ---------------- pools + skip for ALL branches of a step; overwrites dst ----
struct PoolA { const float* xs[5]; long xbs[5]; int goff[5]; int cnt; };

__global__ void __launch_bounds__(256)
pool_skip_all_k(PoolA a, const float* __restrict__ p,
                float* __restrict__ so, long out_bs)
{
    const int c = blockIdx.x, b = blockIdx.y, tid = threadIdx.x;
    __shared__ float t[1024];
    float acc[4] = {0.f, 0.f, 0.f, 0.f};
    for (int j = 0; j < a.cnt; ++j) {
        const float* g = p + a.goff[j] + b * 8;
        float w1 = g[1] * BN_S, w2 = g[2] * BN_S, w3 = g[3];
        if (w1 == 0.f && w2 == 0.f && w3 == 0.f) continue;
        const float* src = a.xs[j] + (long)b * a.xbs[j] + (long)c * 1024;
        __syncthreads();
        for (int i = tid; i < 1024; i += 256) t[i] = src[i];
        __syncthreads();
#pragma unroll
        for (int e = 0; e < 4; ++e) {
            int i = tid + e * 256;
            int h = i >> 5, wx = i & 31;
            int y0 = max(h - 1, 0), y1 = min(h + 1, 31);
            int x0 = max(wx - 1, 0), x1 = min(wx + 1, 31);
            float mx = -3.4e38f, sm = 0.0f;
            for (int y = y0; y <= y1; ++y)
                for (int x = x0; x <= x1; ++x) {
                    float v = t[(y << 5) + x];
                    mx = fmaxf(mx, v); sm += v;
                }
            float cntc = (float)((y1 - y0 + 1) * (x1 - x0 + 1));
            acc[e] += w1 * mx + w2 * (sm / cntc) + w3 * t[i];
        }
    }
    float* dst = so + (long)b * out_bs + (long)c * 1024;
#pragma unroll
    for (int e = 0; e < 4; ++e) dst[tid + e * 256] = acc[e];
}

extern "C" void kernel_launch(void* const* d_in, const int* in_sizes, int n_in,
                              void* d_out, int out_size, void* d_ws, size_t ws_size,
                              hipStream_t stream)
{
    const float* s0   = (const float*)d_in[0];
    const float* s1   = (const float*)d_in[1];
    const float* gts  = (const float*)d_in[2];
    const float* pre0 = (const float*)d_in[3];
    const float* pre1 = (const float*)d_in[4];
    const float* s3d1 = (const float*)d_in[5];
    const float* s3p1 = (const float*)d_in[6];
    const float* s3d2 = (const float*)d_in[7];
    const float* s3p2 = (const float*)d_in[8];
    const float* s5d1 = (const float*)d_in[9];
    const float* s5p1 = (const float*)d_in[10];
    const float* s5d2 = (const float*)d_in[11];
    const float* s5p2 = (const float*)d_in[12];
    const float* d3d  = (const float*)d_in[13];
    const float* d3p  = (const float*)d_in[14];
    const float* d5d  = (const float*)d_in[15];
    const float* d5p  = (const float*)d_in[16];
    const int*   topp = (const int*)d_in[17];
    float* out = (float*)d_out;

    float* ws   = (float*)d_ws;
    float* p    = ws;                          // 4096 floats (3584 used)
    float* s0p  = ws + 4096;                   // [32][128][1024] f32
    float* s1p  = s0p + 4194304;
    short* wb   = (short*)(s1p + 4194304);     // 6 x [14][128][128] bf16
    short* wpre = wb + 1376256;                // 2 x [128][512] bf16
    char*  sl   = (char*)(wpre + 131072);
    uintptr_t ua = ((uintptr_t)sl + 255) & ~(uintptr_t)255;
    short* X    = (short*)ua;                  // nslot x [32][4][128][1024] bf16

    size_t used_base = (size_t)((char*)ua - (char*)d_ws);
    const size_t slot_bytes = 16777216ull * 2 + 8388608ull * 4;  // 64 MB
    int nslot = 1;
    if (ws_size > used_base + slot_bytes)
        nslot = (int)((ws_size - used_base) / slot_bytes);
    if (nslot > 5) nslot = 5;
    if (nslot < 1) nslot = 1;
    float* yb = (float*)(X + (long)nslot * 16777216);  // nslot x [32][2][128][1024] f32

    gates_k<<<2, 256, 0, stream>>>(gts, topp, p);
    cvt_k<<<dim3(224, 8), 256, 0, stream>>>(s3p1, s3p2, s5p1, s5p2, d3p, d5p,
                                            pre0, pre1, wb, wpre);
    pre_k<<<dim3(8, 1, 64), 256, 0, stream>>>(s0, s1, wpre, s0p, s1p);

    const long SB = 131072L, OB = 524288L;
    const float* stp[6]; long sbs[6];
    stp[0] = s0p; sbs[0] = SB;
    stp[1] = s1p; sbs[1] = SB;

    int offset = 0;
    for (int i = 0; i < 4; ++i) {
        float* so = out + (long)i * 131072;
        int cnt = 2 + i;

        PoolA pa{};
        for (int j = 0; j < cnt; ++j) {
            pa.xs[j] = stp[j]; pa.xbs[j] = sbs[j]; pa.goff[j] = (offset + j) * 256;
        }
        pa.cnt = cnt;
        pool_skip_all_k<<<dim3(128, 32), 256, 0, stream>>>(pa, p, so, OB);

        for (int j0 = 0; j0 < cnt; j0 += nslot) {
            int nb = (cnt - j0 < nslot) ? (cnt - j0) : nslot;
            BranchA a{};
            for (int jj = 0; jj < nb; ++jj) {
                int j = j0 + jj, m = offset + j;
                a.xs[jj] = stp[j]; a.xbs[jj] = sbs[j];
                a.goff[jj] = m * 256; a.m[jj] = m;
            }
            a.nb = nb;
            dw1_all<<<dim3(128, 32, nb), 256, 0, stream>>>(a, s3d1, s5d1, d3d, d5d, X, p);
            pw1_all<<<dim3(8, 8, 32 * nb), 256, 0, stream>>>(a, X, wb, yb, p);
            dw2_all<<<dim3(128, 32, 2 * nb), 256, 0, stream>>>(a, yb, s3d2, s5d2, X, p);
            final_all<<<dim3(8, 4, 32), 256, 0, stream>>>(a, X, wb, so, p);
        }
        stp[2 + i] = so; sbs[2 + i] = OB;
        offset += cnt;
    }
}

// Round 3
// 814.674 us; speedup vs baseline: 1.4227x; 1.1480x over previous
//
#include <hip/hip_runtime.h>

#define BN_S 0.9999950000374997f

typedef __attribute__((ext_vector_type(8))) short bf16x8;
typedef __attribute__((ext_vector_type(4))) short s16x4;
typedef __attribute__((ext_vector_type(4))) float f32x4;

__device__ inline short f2bf(float f) {
    union { float f; unsigned u; } v; v.f = f;
    return (short)((v.u + 0x7FFFu + ((v.u >> 16) & 1u)) >> 16);
}

// ---------------- gates: top-k mask + masked softmax -> p[14][32][8] ----------
__global__ void gates_k(const float* __restrict__ g, const int* __restrict__ topp,
                        float* __restrict__ p)
{
    int t = blockIdx.x * blockDim.x + threadIdx.x;
    if (t >= 14 * 32) return;
    int top = topp[0];
    float v[8]; bool sel[8];
    for (int o = 0; o < 8; ++o) { v[o] = g[t * 8 + o]; sel[o] = false; }
    for (int it = 0; it < top; ++it) {
        int bi = 0; float bv = -3.4e38f;
        for (int o = 0; o < 8; ++o)
            if (!sel[o] && v[o] > bv) { bv = v[o]; bi = o; }
        sel[bi] = true;
    }
    float mx = -3.4e38f;
    for (int o = 0; o < 8; ++o) if (sel[o]) mx = fmaxf(mx, v[o]);
    float e[8]; float sum = 0.0f;
    for (int o = 0; o < 8; ++o) { e[o] = sel[o] ? expf(v[o] - mx) : 0.0f; sum += e[o]; }
    for (int o = 0; o < 8; ++o) p[t * 8 + o] = e[o] / sum;
}

// ---------------- one-time: convert all pointwise weights f32 -> bf16 --------
__global__ void cvt_k(const float* __restrict__ s3p1, const float* __restrict__ s3p2,
                      const float* __restrict__ s5p1, const float* __restrict__ s5p2,
                      const float* __restrict__ d3p,  const float* __restrict__ d5p,
                      const float* __restrict__ pre0, const float* __restrict__ pre1,
                      short* __restrict__ wb, short* __restrict__ wpre)
{
    const int which = blockIdx.y;
    const float* src; short* dst; int n;
    switch (which) {
        case 0: src = s3p1; dst = wb;               n = 229376; break;
        case 1: src = s3p2; dst = wb + 229376;      n = 229376; break;
        case 2: src = s5p1; dst = wb + 2 * 229376;  n = 229376; break;
        case 3: src = s5p2; dst = wb + 3 * 229376;  n = 229376; break;
        case 4: src = d3p;  dst = wb + 4 * 229376;  n = 229376; break;
        case 5: src = d5p;  dst = wb + 5 * 229376;  n = 229376; break;
        case 6: src = pre0; dst = wpre;             n = 65536;  break;
        default:src = pre1; dst = wpre + 65536;     n = 65536;  break;
    }
    for (int i = blockIdx.x * 256 + threadIdx.x; i < n; i += gridDim.x * 256)
        dst[i] = f2bf(src[i]);
}

// ---------------- preprocess: K=512 GEMM, 8 waves, LDS-staged B --------------
// grid (8 n-tiles, 1, 64): z -> b | which. 512 threads; wave w owns co rows w*16..+16.
__global__ void __launch_bounds__(512)
pre_k(const float* __restrict__ s0, const float* __restrict__ s1,
      const short* __restrict__ wpre,
      float* __restrict__ s0p, float* __restrict__ s1p)
{
    const int z = blockIdx.z;
    const int b = z & 31, which = z >> 5;
    const float* in = (which ? s1 : s0) + (long)b * 524288;
    const short* w = wpre + which * 65536;
    float* outp = (which ? s1p : s0p) + (long)b * 131072;

    const int tid = threadIdx.x;
    const int wave = tid >> 6, lane = tid & 63;
    const int quad = lane >> 4, l16 = lane & 15;
    const int n0 = blockIdx.x * 128;

    __shared__ short bt[128 * 40];
    const int tn = tid & 127, tk = (tid >> 7) * 8;

    f32x4 acc[8];
#pragma unroll
    for (int i = 0; i < 8; ++i) acc[i] = (f32x4){0.f, 0.f, 0.f, 0.f};

    for (int k0 = 0; k0 < 512; k0 += 32) {
        __syncthreads();
        bf16x8 v;
#pragma unroll
        for (int kk = 0; kk < 8; ++kk)
            v[kk] = f2bf(fmaxf(in[(long)(k0 + tk + kk) * 1024 + n0 + tn], 0.0f));
        *(bf16x8*)&bt[tn * 40 + tk] = v;
        __syncthreads();
        bf16x8 af = *(const bf16x8*)(w + (long)(wave * 16 + l16) * 512 + k0 + quad * 8);
#pragma unroll
        for (int s = 0; s < 8; ++s) {
            bf16x8 bfv = *(const bf16x8*)&bt[(s * 16 + l16) * 40 + quad * 8];
            acc[s] = __builtin_amdgcn_mfma_f32_16x16x32_bf16(af, bfv, acc[s], 0, 0, 0);
        }
    }
#pragma unroll
    for (int s = 0; s < 8; ++s)
#pragma unroll
        for (int r = 0; r < 4; ++r)
            outp[(long)(wave * 16 + quad * 4 + r) * 1024 + n0 + s * 16 + l16] =
                acc[s][r] * BN_S;
}

// ---------------- branch batch descriptor ------------------------------------
struct BranchA {
    const float* xs[5]; long xbs[5];
    int goff[5]; int m[5]; int nb;
};

// X slot layout per branch: [b 32][seg 4][c 128][n 1024] bf16, slot = 16,777,216 sh
// yb slot layout per branch: [b 32][u 2][c 128][n 1024] f32, slot = 8,388,608 f

// ---------------- stage 1: 4 first-stage dwconvs, padded tile, branchless ----
__global__ void __launch_bounds__(256)
dw1_all(BranchA a, const float* __restrict__ s3d1, const float* __restrict__ s5d1,
        const float* __restrict__ d3d, const float* __restrict__ d5d,
        short* __restrict__ X, const float* __restrict__ p)
{
    const int c = blockIdx.x, b = blockIdx.y, j = blockIdx.z;
    const float* pm = p + a.goff[j] + b * 8;
    const float g4 = pm[4], g5 = pm[5], g6 = pm[6], g7 = pm[7];
    if (g4 == 0.f && g5 == 0.f && g6 == 0.f && g7 == 0.f) return;
    const int m = a.m[j];
    __shared__ float t[40 * 40];
    __shared__ float wl[4][25];
    const int tid = threadIdx.x;
    const float* src = a.xs[j] + (long)b * a.xbs[j] + (long)c * 1024;
    for (int i = tid; i < 1600; i += 256) {
        int r = i / 40, col = i - r * 40;
        int y = r - 4, x = col - 4;
        float v = 0.0f;
        if ((unsigned)y < 32u && (unsigned)x < 32u) v = fmaxf(src[(y << 5) + x], 0.0f);
        t[i] = v;
    }
    if (tid < 9)                      wl[0][tid]     = s3d1[(long)m * 1152 + (long)c * 9 + tid];
    else if (tid >= 64 && tid < 89)   wl[1][tid-64]  = s5d1[(long)m * 3200 + (long)c * 25 + tid - 64];
    else if (tid >= 128 && tid < 137) wl[2][tid-128] = d3d[(long)m * 1152 + (long)c * 9 + tid - 128];
    else if (tid >= 192 && tid < 217) wl[3][tid-192] = d5d[(long)m * 3200 + (long)c * 25 + tid - 192];
    __syncthreads();
    short* dst = X + (long)j * 16777216 + (long)b * 524288 + (long)c * 1024;
    const int h = tid >> 3, w0 = (tid & 7) * 4;
    const float* tc = &t[(h + 4) * 40 + (w0 + 4)];
    const float s6 = g6 * BN_S, s7 = g7 * BN_S;

    if (g4 != 0.f) {   // sep3 dw1: 3x3, taps -1..1
        float a0 = 0.f, a1 = 0.f, a2 = 0.f, a3 = 0.f;
#pragma unroll
        for (int ki = 0; ki < 3; ++ki) {
            const float* row = tc + (ki - 1) * 40;
#pragma unroll
            for (int kj = 0; kj < 3; ++kj) {
                float wv = wl[0][ki * 3 + kj];
                a0 += wv * row[kj - 1]; a1 += wv * row[kj];
                a2 += wv * row[kj + 1]; a3 += wv * row[kj + 2];
            }
        }
        *(s16x4*)&dst[tid * 4] = (s16x4){f2bf(a0), f2bf(a1), f2bf(a2), f2bf(a3)};
    }
    if (g5 != 0.f) {   // sep5 dw1: 5x5, taps -2..2
        float a0 = 0.f, a1 = 0.f, a2 = 0.f, a3 = 0.f;
#pragma unroll
        for (int ki = 0; ki < 5; ++ki) {
            const float* row = tc + (ki - 2) * 40;
#pragma unroll
            for (int kj = 0; kj < 5; ++kj) {
                float wv = wl[1][ki * 5 + kj];
                a0 += wv * row[kj - 2]; a1 += wv * row[kj - 1];
                a2 += wv * row[kj];     a3 += wv * row[kj + 1];
            }
        }
        *(s16x4*)&dst[131072 + tid * 4] = (s16x4){f2bf(a0), f2bf(a1), f2bf(a2), f2bf(a3)};
    }
    if (g6 != 0.f) {   // dil3: 3x3 dil2, taps -2,0,2
        float a0 = 0.f, a1 = 0.f, a2 = 0.f, a3 = 0.f;
#pragma unroll
        for (int ki = 0; ki < 3; ++ki) {
            const float* row = tc + (ki * 2 - 2) * 40;
#pragma unroll
            for (int kj = 0; kj < 3; ++kj) {
                float wv = wl[2][ki * 3 + kj];
                int o = kj * 2 - 2;
                a0 += wv * row[o];     a1 += wv * row[o + 1];
                a2 += wv * row[o + 2]; a3 += wv * row[o + 3];
            }
        }
        *(s16x4*)&dst[262144 + tid * 4] =
            (s16x4){f2bf(s6 * a0), f2bf(s6 * a1), f2bf(s6 * a2), f2bf(s6 * a3)};
    }
    if (g7 != 0.f) {   // dil5: 5x5 dil2, taps -4..4 step 2
        float a0 = 0.f, a1 = 0.f, a2 = 0.f, a3 = 0.f;
#pragma unroll
        for (int ki = 0; ki < 5; ++ki) {
            const float* row = tc + (ki * 2 - 4) * 40;
#pragma unroll
            for (int kj = 0; kj < 5; ++kj) {
                float wv = wl[3][ki * 5 + kj];
                int o = kj * 2 - 4;
                a0 += wv * row[o];     a1 += wv * row[o + 1];
                a2 += wv * row[o + 2]; a3 += wv * row[o + 3];
            }
        }
        *(s16x4*)&dst[393216 + tid * 4] =
            (s16x4){f2bf(s7 * a0), f2bf(s7 * a1), f2bf(s7 * a2), f2bf(s7 * a3)};
    }
}

// ---------------- stage 2: pw1 GEMMs (sep3/sep5), all branches ---------------
__global__ void __launch_bounds__(256)
pw1_all(BranchA a, const short* __restrict__ X, const short* __restrict__ wb,
        float* __restrict__ yb, const float* __restrict__ p)
{
    const int z = blockIdx.z, b = z & 31, j = z >> 5;
    const int u = blockIdx.y >> 2, cot = blockIdx.y & 3;
    if (p[a.goff[j] + b * 8 + 4 + u] == 0.f) return;
    const int tid = threadIdx.x;
    const int wave = tid >> 6, lane = tid & 63;
    const int quad = lane >> 4, l16 = lane & 15;
    const int co0 = cot * 32 + (wave & 1) * 16;
    const int n0  = blockIdx.x * 128 + (wave >> 1) * 64;
    const short* w = wb + (u ? 2L * 229376 : 0L) + (long)a.m[j] * 16384;
    const short* xb = X + (long)j * 16777216 + (long)b * 524288 + (long)u * 131072;

    f32x4 acc[4] = {{0,0,0,0},{0,0,0,0},{0,0,0,0},{0,0,0,0}};
    for (int k0 = 0; k0 < 128; k0 += 32) {
        bf16x8 af = *(const bf16x8*)(w + (co0 + l16) * 128 + k0 + quad * 8);
        const short* xc = xb + (long)(k0 + quad * 8) * 1024 + n0 + l16;
#pragma unroll
        for (int s = 0; s < 4; ++s) {
            bf16x8 bfv;
#pragma unroll
            for (int jj = 0; jj < 8; ++jj) bfv[jj] = xc[jj * 1024 + s * 16];
            acc[s] = __builtin_amdgcn_mfma_f32_16x16x32_bf16(af, bfv, acc[s], 0, 0, 0);
        }
    }
    float* dst = yb + (long)j * 8388608 + ((long)b * 2 + u) * 131072;
#pragma unroll
    for (int s = 0; s < 4; ++s)
#pragma unroll
        for (int r = 0; r < 4; ++r)
            dst[(long)(co0 + quad * 4 + r) * 1024 + n0 + s * 16 + l16] =
                fmaxf(acc[s][r] * BN_S, 0.0f);
}

// ---------------- stage 3: second dwconvs, padded tile, branchless -----------
__global__ void __launch_bounds__(256)
dw2_all(BranchA a, const float* __restrict__ yb,
        const float* __restrict__ s3d2, const float* __restrict__ s5d2,
        short* __restrict__ X, const float* __restrict__ p)
{
    const int c = blockIdx.x, b = blockIdx.y;
    const int z = blockIdx.z, u = z & 1, j = z >> 1;
    const float g = p[a.goff[j] + b * 8 + 4 + u];
    if (g == 0.f) return;
    const int m = a.m[j];
    __shared__ float t[36 * 36];
    __shared__ float wl[25];
    const int tid = threadIdx.x;
    const float* src = yb + (long)j * 8388608 + ((long)b * 2 + u) * 131072 + (long)c * 1024;
    for (int i = tid; i < 1296; i += 256) {
        int r = i / 36, col = i - r * 36;
        int y = r - 2, x = col - 2;
        float v = 0.0f;
        if ((unsigned)y < 32u && (unsigned)x < 32u) v = src[(y << 5) + x];
        t[i] = v;
    }
    if (u == 0) { if (tid < 9)  wl[tid] = s3d2[(long)m * 1152 + (long)c * 9  + tid]; }
    else        { if (tid < 25) wl[tid] = s5d2[(long)m * 3200 + (long)c * 25 + tid]; }
    __syncthreads();
    const float sc = g * BN_S;
    short* dst = X + (long)j * 16777216 + (long)b * 524288 + (long)u * 131072 + (long)c * 1024;
    const int h = tid >> 3, w0 = (tid & 7) * 4;
    const float* tc = &t[(h + 2) * 36 + (w0 + 2)];
    float a0 = 0.f, a1 = 0.f, a2 = 0.f, a3 = 0.f;
    if (u == 0) {
#pragma unroll
        for (int ki = 0; ki < 3; ++ki) {
            const float* row = tc + (ki - 1) * 36;
#pragma unroll
            for (int kj = 0; kj < 3; ++kj) {
                float wv = wl[ki * 3 + kj];
                a0 += wv * row[kj - 1]; a1 += wv * row[kj];
                a2 += wv * row[kj + 1]; a3 += wv * row[kj + 2];
            }
        }
    } else {
#pragma unroll
        for (int ki = 0; ki < 5; ++ki) {
            const float* row = tc + (ki - 2) * 36;
#pragma unroll
            for (int kj = 0; kj < 5; ++kj) {
                float wv = wl[ki * 5 + kj];
                a0 += wv * row[kj - 2]; a1 += wv * row[kj - 1];
                a2 += wv * row[kj];     a3 += wv * row[kj + 1];
            }
        }
    }
    *(s16x4*)&dst[tid * 4] =
        (s16x4){f2bf(sc * a0), f2bf(sc * a1), f2bf(sc * a2), f2bf(sc * a3)};
}

// ---------------- stage 4: fused gated GEMM over all branches & segs ---------
__global__ void __launch_bounds__(256)
final_all(BranchA a, const short* __restrict__ X, const short* __restrict__ wb,
          float* __restrict__ outp, const float* __restrict__ p)
{
    const int b = blockIdx.z;
    const int tid = threadIdx.x;
    const int wave = tid >> 6, lane = tid & 63;
    const int quad = lane >> 4, l16 = lane & 15;
    const int co0 = blockIdx.y * 32 + (wave & 1) * 16;
    const int n0  = blockIdx.x * 128 + (wave >> 1) * 64;

    f32x4 acc[4] = {{0,0,0,0},{0,0,0,0},{0,0,0,0},{0,0,0,0}};
    bool any = false;
    for (int j = 0; j < a.nb; ++j) {
        const float* pm = p + a.goff[j] + b * 8;
        const short* xj = X + (long)j * 16777216 + (long)b * 524288;
        const long wm = (long)a.m[j] * 16384;
        const short* ws_[4] = { wb + 1L * 229376 + wm, wb + 3L * 229376 + wm,
                                wb + 4L * 229376 + wm, wb + 5L * 229376 + wm };
#pragma unroll
        for (int seg = 0; seg < 4; ++seg) {
            if (pm[4 + seg] == 0.f) continue;
            any = true;
            const short* w = ws_[seg];
            const short* xs = xj + (long)seg * 131072;
            for (int k0 = 0; k0 < 128; k0 += 32) {
                bf16x8 af = *(const bf16x8*)(w + (co0 + l16) * 128 + k0 + quad * 8);
                const short* xc = xs + (long)(k0 + quad * 8) * 1024 + n0 + l16;
#pragma unroll
                for (int s = 0; s < 4; ++s) {
                    bf16x8 bfv;
#pragma unroll
                    for (int jj = 0; jj < 8; ++jj) bfv[jj] = xc[jj * 1024 + s * 16];
                    acc[s] = __builtin_amdgcn_mfma_f32_16x16x32_bf16(af, bfv, acc[s], 0, 0, 0);
                }
            }
        }
    }
    if (!any) return;
#pragma unroll
    for (int s = 0; s < 4; ++s)
#pragma unroll
        for (int r = 0; r < 4; ++r) {
            long idx = (long)b * 524288 + (long)(co0 + quad * 4 + r) * 1024
                     + n0 + s * 16 + l16;
            outp[idx] += acc[s][r];
        }
}

// ---------------- pools + skip for ALL branches of a step; overwrites dst ----
struct PoolA { const float* xs[5]; long xbs[5]; int goff[5]; int cnt; };

__global__ void __launch_bounds__(256)
pool_skip_all_k(PoolA a, const float* __restrict__ p,
                float* __restrict__ so, long out_bs)
{
    const int c = blockIdx.x, b = blockIdx.y, tid = threadIdx.x;
    __shared__ float t[1024];
    float acc[4] = {0.f, 0.f, 0.f, 0.f};
    for (int j = 0; j < a.cnt; ++j) {
        const float* g = p + a.goff[j] + b * 8;
        float w1 = g[1] * BN_S, w2 = g[2] * BN_S, w3 = g[3];
        if (w1 == 0.f && w2 == 0.f && w3 == 0.f) continue;
        const float* src = a.xs[j] + (long)b * a.xbs[j] + (long)c * 1024;
        __syncthreads();
        for (int i = tid; i < 1024; i += 256) t[i] = src[i];
        __syncthreads();
#pragma unroll
        for (int e = 0; e < 4; ++e) {
            int i = tid + e * 256;
            int h = i >> 5, wx = i & 31;
            int y0 = max(h - 1, 0), y1 = min(h + 1, 31);
            int x0 = max(wx - 1, 0), x1 = min(wx + 1, 31);
            float mx = -3.4e38f, sm = 0.0f;
            for (int y = y0; y <= y1; ++y)
                for (int x = x0; x <= x1; ++x) {
                    float v = t[(y << 5) + x];
                    mx = fmaxf(mx, v); sm += v;
                }
            float cntc = (float)((y1 - y0 + 1) * (x1 - x0 + 1));
            acc[e] += w1 * mx + w2 * (sm / cntc) + w3 * t[i];
        }
    }
    float* dst = so + (long)b * out_bs + (long)c * 1024;
#pragma unroll
    for (int e = 0; e < 4; ++e) dst[tid + e * 256] = acc[e];
}

extern "C" void kernel_launch(void* const* d_in, const int* in_sizes, int n_in,
                              void* d_out, int out_size, void* d_ws, size_t ws_size,
                              hipStream_t stream)
{
    const float* s0   = (const float*)d_in[0];
    const float* s1   = (const float*)d_in[1];
    const float* gts  = (const float*)d_in[2];
    const float* pre0 = (const float*)d_in[3];
    const float* pre1 = (const float*)d_in[4];
    const float* s3d1 = (const float*)d_in[5];
    const float* s3p1 = (const float*)d_in[6];
    const float* s3d2 = (const float*)d_in[7];
    const float* s3p2 = (const float*)d_in[8];
    const float* s5d1 = (const float*)d_in[9];
    const float* s5p1 = (const float*)d_in[10];
    const float* s5d2 = (const float*)d_in[11];
    const float* s5p2 = (const float*)d_in[12];
    const float* d3d  = (const float*)d_in[13];
    const float* d3p  = (const float*)d_in[14];
    const float* d5d  = (const float*)d_in[15];
    const float* d5p  = (const float*)d_in[16];
    const int*   topp = (const int*)d_in[17];
    float* out = (float*)d_out;

    float* ws   = (float*)d_ws;
    float* p    = ws;                          // 4096 floats (3584 used)
    float* s0p  = ws + 4096;                   // [32][128][1024] f32
    float* s1p  = s0p + 4194304;
    short* wb   = (short*)(s1p + 4194304);     // 6 x [14][128][128] bf16
    short* wpre = wb + 1376256;                // 2 x [128][512] bf16
    char*  sl   = (char*)(wpre + 131072);
    uintptr_t ua = ((uintptr_t)sl + 255) & ~(uintptr_t)255;
    short* X    = (short*)ua;                  // nslot x [32][4][128][1024] bf16

    size_t used_base = (size_t)((char*)ua - (char*)d_ws);
    const size_t slot_bytes = 16777216ull * 2 + 8388608ull * 4;  // 64 MB
    int nslot = 1;
    if (ws_size > used_base + slot_bytes)
        nslot = (int)((ws_size - used_base) / slot_bytes);
    if (nslot > 5) nslot = 5;
    if (nslot < 1) nslot = 1;
    float* yb = (float*)(X + (long)nslot * 16777216);  // nslot x [32][2][128][1024] f32

    gates_k<<<2, 256, 0, stream>>>(gts, topp, p);
    cvt_k<<<dim3(224, 8), 256, 0, stream>>>(s3p1, s3p2, s5p1, s5p2, d3p, d5p,
                                            pre0, pre1, wb, wpre);
    pre_k<<<dim3(8, 1, 64), 512, 0, stream>>>(s0, s1, wpre, s0p, s1p);

    const long SB = 131072L, OB = 524288L;
    const float* stp[6]; long sbs[6];
    stp[0] = s0p; sbs[0] = SB;
    stp[1] = s1p; sbs[1] = SB;

    int offset = 0;
    for (int i = 0; i < 4; ++i) {
        float* so = out + (long)i * 131072;
        int cnt = 2 + i;

        PoolA pa{};
        for (int j = 0; j < cnt; ++j) {
            pa.xs[j] = stp[j]; pa.xbs[j] = sbs[j]; pa.goff[j] = (offset + j) * 256;
        }
        pa.cnt = cnt;
        pool_skip_all_k<<<dim3(128, 32), 256, 0, stream>>>(pa, p, so, OB);

        for (int j0 = 0; j0 < cnt; j0 += nslot) {
            int nb = (cnt - j0 < nslot) ? (cnt - j0) : nslot;
            BranchA a{};
            for (int jj = 0; jj < nb; ++jj) {
                int j = j0 + jj, m = offset + j;
                a.xs[jj] = stp[j]; a.xbs[jj] = sbs[j];
                a.goff[jj] = m * 256; a.m[jj] = m;
            }
            a.nb = nb;
            dw1_all<<<dim3(128, 32, nb), 256, 0, stream>>>(a, s3d1, s5d1, d3d, d5d, X, p);
            pw1_all<<<dim3(8, 8, 32 * nb), 256, 0, stream>>>(a, X, wb, yb, p);
            dw2_all<<<dim3(128, 32, 2 * nb), 256, 0, stream>>>(a, yb, s3d2, s5d2, X, p);
            final_all<<<dim3(8, 4, 32), 256, 0, stream>>>(a, X, wb, so, p);
        }
        stp[2 + i] = so; sbs[2 + i] = OB;
        offset += cnt;
    }
}